// Round 10
// baseline (181.172 us; speedup 1.0000x reference)
//
#include <hip/hip_runtime.h>

#define N_NODES 100000
#define D_INF   128
#define D_HID   256
#define K_CL    16
#define N_TILES (N_NODES / 16)       // 6250, exact
#define N_EDGES 3200000
#define EDGE_BLOCKS (N_EDGES / 1024) // 3125: 4 waves x 256 edges

typedef __attribute__((ext_vector_type(8))) __bf16  bf16x8;
typedef __attribute__((ext_vector_type(8))) unsigned short u16x8;
typedef __attribute__((ext_vector_type(4))) float   f32x4;
typedef __attribute__((ext_vector_type(4))) unsigned int u32x4;

__device__ __forceinline__ unsigned short f2bf(float f) {
    unsigned int u = __builtin_bit_cast(unsigned int, f);
    u += 0x7fffu + ((u >> 16) & 1u);          // RNE
    return (unsigned short)(u >> 16);
}
__device__ __forceinline__ float bflo(unsigned int p) {
    return __builtin_bit_cast(float, p << 16);
}
__device__ __forceinline__ float bfhi(unsigned int p) {
    return __builtin_bit_cast(float, p & 0xffff0000u);
}

// ---------------------------------------------------------------------------
// Prep: W1 [128][256] f32 -> W1T [256][128] bf16 ; W2 [256][16] f32 -> W2T
// [16][256] bf16. Writes coalesced.
// ---------------------------------------------------------------------------
__global__ void prep_kernel(const float* __restrict__ W1,
                            const float* __restrict__ W2,
                            unsigned short* __restrict__ w1t,
                            unsigned short* __restrict__ w2t)
{
    const int i = blockIdx.x * 256 + threadIdx.x;
    if (i < D_INF * D_HID) {                  // w1t[n][k] = W1[k][n]
        const int n = i >> 7, k = i & 127;
        w1t[i] = f2bf(W1[k * D_HID + n]);
    }
    if (i < D_HID * K_CL) {                   // w2t[t][n] = W2[n][t]
        const int t = i >> 8, n = i & 255;
        w2t[i] = f2bf(W2[n * K_CL + t]);
    }
}

// ---------------------------------------------------------------------------
// Fused MLP v6 = v5 + REGISTER PINNING. R9's counters showed VGPR_Count=64:
// the compiler rematerialized the "loop-invariant" W1 fragment loads into
// the tile loop (re-reading W1T from L2 every tile -> latency-bound).
// The empty asm below makes each fragment opaque, forcing it to stay
// resident in VGPRs across the whole tile loop.
// Wave w owns hidden cols [64w, 64w+64): B-frags = 16 x b128 = 64 VGPRs.
// Per tile: 16 register-fed GEMM1 MFMA -> h to wave-private LDS -> 2 GEMM2
// partial MFMA -> one __syncthreads + 4-way LDS logit reduction -> softmax;
// wave w stores rows 4w..4w+3. LDS 18,432 B -> 3 blocks/CU, 12 waves/CU.
// ---------------------------------------------------------------------------
#define CHS 40       // LDS row stride (bf16) for h chunks

__global__ __launch_bounds__(256, 3) void mlp_kernel(
    const float* __restrict__ x, const unsigned short* __restrict__ W1T,
    const float* __restrict__ b1, const unsigned short* __restrict__ W2T,
    const float* __restrict__ b2, float* __restrict__ C,
    unsigned short* __restrict__ Cb)
{
    __shared__ unsigned short hbuf[4][2][16 * CHS];   // 10,240 B
    __shared__ f32x4 pbuf[2][4][64];                  //  8,192 B -> 18,432

    const int tid  = threadIdx.x;
    const int wv   = tid >> 6;
    const int lane = tid & 63;
    const int c    = lane & 15;
    const int q    = lane >> 4;

    // ---- loop-invariant registers, PINNED so they can't be rematerialized
    u32x4 bfr[4][4];                 // 64 VGPRs of W1T fragments
    #pragma unroll
    for (int i = 0; i < 4; ++i)
        #pragma unroll
        for (int kc = 0; kc < 4; ++kc) {
            bfr[i][kc] = *(const u32x4*)(
                W1T + (size_t)((4 * wv + i) * 16 + c) * D_INF + kc * 32 + q * 8);
            asm volatile("" : "+v"(bfr[i][kc]));
        }
    u32x4 w2f[2];                    // 8 VGPRs of W2T fragments
    #pragma unroll
    for (int j = 0; j < 2; ++j) {
        w2f[j] = *(const u32x4*)(
            W2T + (size_t)c * D_HID + (2 * wv + j) * 32 + q * 8);
        asm volatile("" : "+v"(w2f[j]));
    }
    float b1v[4];
    #pragma unroll
    for (int i = 0; i < 4; ++i) b1v[i] = b1[(4 * wv + i) * 16 + c];
    const float b2v = b2[c];

    unsigned short* const ch0 = &hbuf[wv][0][0];
    unsigned short* const ch1 = &hbuf[wv][1][0];

    int p = 0;
    for (int tile = blockIdx.x; tile < N_TILES; tile += gridDim.x) {
        const int m0 = tile * 16;

        // ---- A fragments: x row m0+c, fp32 -> bf16 (16 VGPRs) ----
        const float* xrow = x + (size_t)(m0 + c) * D_INF + q * 8;
        bf16x8 afr[4];
        #pragma unroll
        for (int kc = 0; kc < 4; ++kc) {
            const float4 xa = *(const float4*)(xrow + kc * 32);
            const float4 xb = *(const float4*)(xrow + kc * 32 + 4);
            u16x8 af;
            af[0] = f2bf(xa.x); af[1] = f2bf(xa.y); af[2] = f2bf(xa.z); af[3] = f2bf(xa.w);
            af[4] = f2bf(xb.x); af[5] = f2bf(xb.y); af[6] = f2bf(xb.z); af[7] = f2bf(xb.w);
            afr[kc] = __builtin_bit_cast(bf16x8, af);
        }

        // ---- GEMM1 (register-fed) + h writes to wave-private LDS ----
        #pragma unroll
        for (int i = 0; i < 4; ++i) {
            f32x4 a1 = (f32x4){0.f, 0.f, 0.f, 0.f};
            #pragma unroll
            for (int kc = 0; kc < 4; ++kc)
                a1 = __builtin_amdgcn_mfma_f32_16x16x32_bf16(
                    afr[kc], __builtin_bit_cast(bf16x8, bfr[i][kc]), a1, 0, 0, 0);
            const float bv = b1v[i];
            unsigned short* const cb = (i >> 1) ? ch1 : ch0;
            const int colb = (i & 1) * 16 + c;
            #pragma unroll
            for (int r = 0; r < 4; ++r)
                cb[(4 * q + r) * CHS + colb] = f2bf(fmaxf(a1[r] + bv, 0.f));
        }

        // ---- GEMM2 partial over own 64 hidden cols (2 MFMA) ----
        f32x4 acc2 = (f32x4){0.f, 0.f, 0.f, 0.f};
        {
            const bf16x8 a20 = *(const bf16x8*)&ch0[c * CHS + q * 8];
            acc2 = __builtin_amdgcn_mfma_f32_16x16x32_bf16(
                a20, __builtin_bit_cast(bf16x8, w2f[0]), acc2, 0, 0, 0);
            const bf16x8 a21 = *(const bf16x8*)&ch1[c * CHS + q * 8];
            acc2 = __builtin_amdgcn_mfma_f32_16x16x32_bf16(
                a21, __builtin_bit_cast(bf16x8, w2f[1]), acc2, 0, 0, 0);
        }

        // ---- cross-wave reduction (double-buffered, one sync/tile) ----
        pbuf[p][wv][lane] = acc2;
        __syncthreads();
        f32x4 lg = pbuf[p][0][lane];
        #pragma unroll
        for (int j = 1; j < 4; ++j) {
            const f32x4 o = pbuf[p][j][lane];
            lg[0] += o[0]; lg[1] += o[1]; lg[2] += o[2]; lg[3] += o[3];
        }
        p ^= 1;

        // ---- softmax per row m = 4q+r across 16 c-lanes ----
        #pragma unroll
        for (int r = 0; r < 4; ++r) {
            const float l = lg[r] + b2v;
            float mx = l;
            mx = fmaxf(mx, __shfl_xor(mx, 1));
            mx = fmaxf(mx, __shfl_xor(mx, 2));
            mx = fmaxf(mx, __shfl_xor(mx, 4));
            mx = fmaxf(mx, __shfl_xor(mx, 8));
            const float e = __expf(l - mx);
            float sm = e;
            sm += __shfl_xor(sm, 1);
            sm += __shfl_xor(sm, 2);
            sm += __shfl_xor(sm, 4);
            sm += __shfl_xor(sm, 8);
            if (q == wv) {                       // wave w stores rows 4w+r
                const float pr = e / sm;
                const size_t o = (size_t)(m0 + 4 * q + r) * K_CL + c;
                C[o]  = pr;
                Cb[o] = f2bf(pr);
            }
        }
    }
}

// ---------------------------------------------------------------------------
// Edge reduction: one-shot, 256 edges per wave (16 independent gathers in
// flight). Coalesced idx loads -> shfl broadcast -> 2 lanes/edge uint4
// gathers from bf16 C copy (3.2 MB, L2-resident). Block partial -> plain
// store (no atomics).
// ---------------------------------------------------------------------------
__global__ __launch_bounds__(256) void edge_kernel(
    const int* __restrict__ ei, const unsigned short* __restrict__ Cb,
    float* __restrict__ partials)
{
    __shared__ float red[4];
    const int tid  = threadIdx.x;
    const int lane = tid & 63;
    const int wv   = tid >> 6;
    const int base = (blockIdx.x * 4 + wv) * 256;

    int u[4], v[4];
    #pragma unroll
    for (int j = 0; j < 4; ++j) {
        u[j] = ei[base + j * 64 + lane];
        v[j] = ei[N_EDGES + base + j * 64 + lane];
    }

    const int half8 = (lane & 1) * 8;    // which 16 B of the 32 B row
    const int sl    = lane >> 1;

    float s = 0.f;
    #pragma unroll
    for (int g = 0; g < 8; ++g) {
        const int src = (g & 1) * 32 + sl;
        const int ue  = __shfl(u[g >> 1], src);
        const int ve  = __shfl(v[g >> 1], src);
        const uint4 a = *(const uint4*)(Cb + (size_t)ue * K_CL + half8);
        const uint4 b = *(const uint4*)(Cb + (size_t)ve * K_CL + half8);
        s = fmaf(bflo(a.x), bflo(b.x), s);
        s = fmaf(bfhi(a.x), bfhi(b.x), s);
        s = fmaf(bflo(a.y), bflo(b.y), s);
        s = fmaf(bfhi(a.y), bfhi(b.y), s);
        s = fmaf(bflo(a.z), bflo(b.z), s);
        s = fmaf(bfhi(a.z), bfhi(b.z), s);
        s = fmaf(bflo(a.w), bflo(b.w), s);
        s = fmaf(bfhi(a.w), bfhi(b.w), s);
    }
    s += __shfl_xor(s, 1);
    s += __shfl_xor(s, 2);
    s += __shfl_xor(s, 4);
    s += __shfl_xor(s, 8);
    s += __shfl_xor(s, 16);
    s += __shfl_xor(s, 32);
    if (lane == 0) red[wv] = s;
    __syncthreads();
    if (tid == 0) partials[blockIdx.x] = red[0] + red[1] + red[2] + red[3];
}

// ---------------------------------------------------------------------------
// Finalize: reduce 3125 block partials, write -sum/E.
// ---------------------------------------------------------------------------
__global__ __launch_bounds__(256) void finalize_kernel(
    const float* __restrict__ partials, float* __restrict__ out)
{
    __shared__ float red[4];
    const int tid = threadIdx.x;
    float s = 0.f;
    for (int i = tid; i < EDGE_BLOCKS; i += 256) s += partials[i];
    s += __shfl_xor(s, 1);
    s += __shfl_xor(s, 2);
    s += __shfl_xor(s, 4);
    s += __shfl_xor(s, 8);
    s += __shfl_xor(s, 16);
    s += __shfl_xor(s, 32);
    if ((tid & 63) == 0) red[tid >> 6] = s;
    __syncthreads();
    if (tid == 0)
        out[(size_t)N_NODES * K_CL] =
            -(red[0] + red[1] + red[2] + red[3]) / (float)N_EDGES;
}

// ---------------------------------------------------------------------------
extern "C" void kernel_launch(void* const* d_in, const int* in_sizes, int n_in,
                              void* d_out, int out_size, void* d_ws, size_t ws_size,
                              hipStream_t stream) {
    const float* x  = (const float*)d_in[0];
    const int*   ei = (const int*)  d_in[1];
    const float* W1 = (const float*)d_in[2];
    const float* b1 = (const float*)d_in[3];
    const float* W2 = (const float*)d_in[4];
    const float* b2 = (const float*)d_in[5];
    float* out = (float*)d_out;

    // ws: W1T bf16 @0 (64 KB), W2T bf16 @65536 (8 KB),
    //     Cb bf16 [100000*16] @73760 (3.2 MB), partials f32 @3273760 (12.5 KB)
    unsigned short* w1t      = (unsigned short*)d_ws;
    unsigned short* w2t      = (unsigned short*)((char*)d_ws + 65536);
    unsigned short* Cb       = (unsigned short*)((char*)d_ws + 73760);
    float*          partials = (float*)((char*)d_ws + 3273760);

    prep_kernel<<<128, 256, 0, stream>>>(W1, W2, w1t, w2t);
    mlp_kernel<<<768, 256, 0, stream>>>(x, w1t, b1, w2t, b2, out, Cb);
    edge_kernel<<<EDGE_BLOCKS, 256, 0, stream>>>(ei, Cb, partials);
    finalize_kernel<<<1, 256, 0, stream>>>(partials, out);
}

// Round 11
// 154.601 us; speedup vs baseline: 1.1719x; 1.1719x over previous
//
#include <hip/hip_runtime.h>

#define N_NODES 100000
#define D_INF   128
#define D_HID   256
#define K_CL    16
#define N_TILES (N_NODES / 16)       // 6250, exact
#define N_EDGES 3200000
#define EDGE_BLOCKS (N_EDGES / 1024) // 3125: 4 waves x 256 edges

typedef __attribute__((ext_vector_type(8))) __bf16  bf16x8;
typedef __attribute__((ext_vector_type(8))) unsigned short u16x8;
typedef __attribute__((ext_vector_type(4))) float   f32x4;

__device__ __forceinline__ unsigned short f2bf(float f) {
    unsigned int u = __builtin_bit_cast(unsigned int, f);
    u += 0x7fffu + ((u >> 16) & 1u);          // RNE
    return (unsigned short)(u >> 16);
}
__device__ __forceinline__ float bflo(unsigned int p) {
    return __builtin_bit_cast(float, p << 16);
}
__device__ __forceinline__ float bfhi(unsigned int p) {
    return __builtin_bit_cast(float, p & 0xffff0000u);
}

// ---------------------------------------------------------------------------
// Prep: W1 [128][256] f32 -> W1T [256][128] bf16 ; W2 [256][16] f32 -> W2T
// [16][256] bf16. Writes coalesced.
// ---------------------------------------------------------------------------
__global__ void prep_kernel(const float* __restrict__ W1,
                            const float* __restrict__ W2,
                            unsigned short* __restrict__ w1t,
                            unsigned short* __restrict__ w2t)
{
    const int i = blockIdx.x * 256 + threadIdx.x;
    if (i < D_INF * D_HID) {                  // w1t[n][k] = W1[k][n]
        const int n = i >> 7, k = i & 127;
        w1t[i] = f2bf(W1[k * D_HID + n]);
    }
    if (i < D_HID * K_CL) {                   // w2t[t][n] = W2[n][t]
        const int t = i >> 8, n = i & 255;
        w2t[i] = f2bf(W2[n * K_CL + t]);
    }
}

// ---------------------------------------------------------------------------
// Fused MLP (R6 structure + x PREFETCH). MFMA 16x16x32 bf16. Block = 4
// waves; wave = one 16-node tile, grid-stride over 6250 tiles (512 blocks).
// W1T staged in LDS per block. Register-pressure-shaped K-loop: one hidden
// 16-col accumulator live at a time; h chunk round-trips through per-wave
// LDS (in-wave DS ordering, no __syncthreads in the loop).
// NEW: next tile's 8 raw float4 x loads are issued at the TOP of each
// iteration (independent of current compute) and consumed next iteration --
// overlaps the per-tile HBM/L3 latency with ~2500 cyc of MFMA/softmax.
// +32 VGPRs is free: occupancy is LDS-capped at 2 blocks/CU (2 waves/SIMD
// -> 256-VGPR budget).
// ---------------------------------------------------------------------------
#define W1S 136      // LDS row stride (bf16) for W1T
#define CHS 40       // LDS row stride (bf16) for h chunk

__global__ __launch_bounds__(256, 2) void mlp_kernel(
    const float* __restrict__ x, const unsigned short* __restrict__ W1T,
    const float* __restrict__ b1, const unsigned short* __restrict__ W2T,
    const float* __restrict__ b2, float* __restrict__ C,
    unsigned short* __restrict__ Cb)
{
    __shared__ unsigned short w1s[256 * W1S];          // 69,632 B
    __shared__ unsigned short chbuf[4][2][16 * CHS];   // 10,240 B
    __shared__ float b1s[D_HID];                       //  1,024 B -> 80,896

    const int tid  = threadIdx.x;
    const int wv   = tid >> 6;
    const int lane = tid & 63;
    const int c    = lane & 15;
    const int q    = lane >> 4;

    // ---- stage W1T into LDS (coalesced uint4 reads, b128 LDS writes) ----
    #pragma unroll
    for (int it = 0; it < 16; ++it) {
        const int idx = it * 256 + tid;        // 4096 uint4 chunks
        const int row = idx >> 4, ch = idx & 15;
        const uint4 v = ((const uint4*)W1T)[idx];
        *(uint4*)&w1s[row * W1S + ch * 8] = v;
    }
    if (tid < D_HID) b1s[tid] = b1[tid];

    // ---- loop-invariant registers: W2T fragments (32 VGPRs), b2 ----
    bf16x8 w2f[8];
    #pragma unroll
    for (int kc2 = 0; kc2 < 8; ++kc2)
        w2f[kc2] = *(const bf16x8*)(W2T + (size_t)c * D_HID + kc2 * 32 + q * 8);
    const float b2v = b2[c];
    __syncthreads();

    unsigned short* const chA = &chbuf[wv][0][0];
    unsigned short* const chB = &chbuf[wv][1][0];

    const int wid     = blockIdx.x * 4 + wv;
    const int wstride = gridDim.x * 4;

    // ---- preload first tile's raw x (8 float4 = 32 VGPRs) ----
    float4 xraw[8];
    {
        const float* xr = x + (size_t)(wid * 16 + c) * D_INF + q * 8;
        #pragma unroll
        for (int j = 0; j < 8; ++j)
            xraw[j] = *(const float4*)(xr + (j >> 1) * 32 + (j & 1) * 4);
    }

    for (int tile = wid; tile < N_TILES; tile += wstride) {
        const int m0 = tile * 16;

        // ---- issue NEXT tile's x loads first (latency overlapped) ----
        const int nxt = tile + wstride;
        float4 xnxt[8];
        if (nxt < N_TILES) {
            const float* xr = x + (size_t)(nxt * 16 + c) * D_INF + q * 8;
            #pragma unroll
            for (int j = 0; j < 8; ++j)
                xnxt[j] = *(const float4*)(xr + (j >> 1) * 32 + (j & 1) * 4);
        }

        // ---- convert CURRENT tile's preloaded x -> A fragments ----
        bf16x8 afr[4];
        #pragma unroll
        for (int kc = 0; kc < 4; ++kc) {
            const float4 xa = xraw[kc * 2], xb = xraw[kc * 2 + 1];
            u16x8 af;
            af[0] = f2bf(xa.x); af[1] = f2bf(xa.y); af[2] = f2bf(xa.z); af[3] = f2bf(xa.w);
            af[4] = f2bf(xb.x); af[5] = f2bf(xb.y); af[6] = f2bf(xb.z); af[7] = f2bf(xb.w);
            afr[kc] = __builtin_bit_cast(bf16x8, af);
        }

        // ---- fused GEMM1 -> h chunk -> GEMM2, one nt-pair at a time ----
        f32x4 acc2 = (f32x4){0.f, 0.f, 0.f, 0.f};
        #pragma unroll
        for (int kc2 = 0; kc2 < 8; ++kc2) {
            unsigned short* const cb = (kc2 & 1) ? chB : chA;
            #pragma unroll
            for (int half = 0; half < 2; ++half) {
                const int nt = kc2 * 2 + half;
                f32x4 a1 = (f32x4){0.f, 0.f, 0.f, 0.f};
                #pragma unroll
                for (int kc = 0; kc < 4; ++kc) {
                    const bf16x8 bf =
                        *(const bf16x8*)&w1s[(nt * 16 + c) * W1S + kc * 32 + q * 8];
                    a1 = __builtin_amdgcn_mfma_f32_16x16x32_bf16(afr[kc], bf, a1, 0, 0, 0);
                }
                const float bv = b1s[nt * 16 + c];
                #pragma unroll
                for (int r = 0; r < 4; ++r)
                    cb[(4 * q + r) * CHS + half * 16 + c] =
                        f2bf(fmaxf(a1[r] + bv, 0.f));
            }
            const bf16x8 a2 = *(const bf16x8*)&cb[c * CHS + q * 8];
            acc2 = __builtin_amdgcn_mfma_f32_16x16x32_bf16(a2, w2f[kc2], acc2, 0, 0, 0);
        }

        // ---- softmax per row m = 4q+r across 16 c-lanes; dual store ----
        #pragma unroll
        for (int r = 0; r < 4; ++r) {
            const float l = acc2[r] + b2v;
            float mx = l;
            mx = fmaxf(mx, __shfl_xor(mx, 1));
            mx = fmaxf(mx, __shfl_xor(mx, 2));
            mx = fmaxf(mx, __shfl_xor(mx, 4));
            mx = fmaxf(mx, __shfl_xor(mx, 8));
            const float e = __expf(l - mx);
            float sm = e;
            sm += __shfl_xor(sm, 1);
            sm += __shfl_xor(sm, 2);
            sm += __shfl_xor(sm, 4);
            sm += __shfl_xor(sm, 8);
            const float p = e / sm;
            const size_t o = (size_t)(m0 + 4 * q + r) * K_CL + c;
            C[o]  = p;
            Cb[o] = f2bf(p);
        }

        // ---- rotate prefetched x into place ----
        if (nxt < N_TILES) {
            #pragma unroll
            for (int j = 0; j < 8; ++j) xraw[j] = xnxt[j];
        }
    }
}

// ---------------------------------------------------------------------------
// Edge reduction: one-shot, 256 edges per wave (16 independent gathers in
// flight). Coalesced idx loads -> shfl broadcast -> 2 lanes/edge uint4
// gathers from bf16 C copy (3.2 MB, L2-resident). Block partial -> plain
// store (no atomics).
// ---------------------------------------------------------------------------
__global__ __launch_bounds__(256) void edge_kernel(
    const int* __restrict__ ei, const unsigned short* __restrict__ Cb,
    float* __restrict__ partials)
{
    __shared__ float red[4];
    const int tid  = threadIdx.x;
    const int lane = tid & 63;
    const int wv   = tid >> 6;
    const int base = (blockIdx.x * 4 + wv) * 256;

    int u[4], v[4];
    #pragma unroll
    for (int j = 0; j < 4; ++j) {
        u[j] = ei[base + j * 64 + lane];
        v[j] = ei[N_EDGES + base + j * 64 + lane];
    }

    const int half8 = (lane & 1) * 8;    // which 16 B of the 32 B row
    const int sl    = lane >> 1;

    float s = 0.f;
    #pragma unroll
    for (int g = 0; g < 8; ++g) {
        const int src = (g & 1) * 32 + sl;
        const int ue  = __shfl(u[g >> 1], src);
        const int ve  = __shfl(v[g >> 1], src);
        const uint4 a = *(const uint4*)(Cb + (size_t)ue * K_CL + half8);
        const uint4 b = *(const uint4*)(Cb + (size_t)ve * K_CL + half8);
        s = fmaf(bflo(a.x), bflo(b.x), s);
        s = fmaf(bfhi(a.x), bfhi(b.x), s);
        s = fmaf(bflo(a.y), bflo(b.y), s);
        s = fmaf(bfhi(a.y), bfhi(b.y), s);
        s = fmaf(bflo(a.z), bflo(b.z), s);
        s = fmaf(bfhi(a.z), bfhi(b.z), s);
        s = fmaf(bflo(a.w), bflo(b.w), s);
        s = fmaf(bfhi(a.w), bfhi(b.w), s);
    }
    s += __shfl_xor(s, 1);
    s += __shfl_xor(s, 2);
    s += __shfl_xor(s, 4);
    s += __shfl_xor(s, 8);
    s += __shfl_xor(s, 16);
    s += __shfl_xor(s, 32);
    if (lane == 0) red[wv] = s;
    __syncthreads();
    if (tid == 0) partials[blockIdx.x] = red[0] + red[1] + red[2] + red[3];
}

// ---------------------------------------------------------------------------
// Finalize: reduce 3125 block partials, write -sum/E.
// ---------------------------------------------------------------------------
__global__ __launch_bounds__(256) void finalize_kernel(
    const float* __restrict__ partials, float* __restrict__ out)
{
    __shared__ float red[4];
    const int tid = threadIdx.x;
    float s = 0.f;
    for (int i = tid; i < EDGE_BLOCKS; i += 256) s += partials[i];
    s += __shfl_xor(s, 1);
    s += __shfl_xor(s, 2);
    s += __shfl_xor(s, 4);
    s += __shfl_xor(s, 8);
    s += __shfl_xor(s, 16);
    s += __shfl_xor(s, 32);
    if ((tid & 63) == 0) red[tid >> 6] = s;
    __syncthreads();
    if (tid == 0)
        out[(size_t)N_NODES * K_CL] =
            -(red[0] + red[1] + red[2] + red[3]) / (float)N_EDGES;
}

// ---------------------------------------------------------------------------
extern "C" void kernel_launch(void* const* d_in, const int* in_sizes, int n_in,
                              void* d_out, int out_size, void* d_ws, size_t ws_size,
                              hipStream_t stream) {
    const float* x  = (const float*)d_in[0];
    const int*   ei = (const int*)  d_in[1];
    const float* W1 = (const float*)d_in[2];
    const float* b1 = (const float*)d_in[3];
    const float* W2 = (const float*)d_in[4];
    const float* b2 = (const float*)d_in[5];
    float* out = (float*)d_out;

    // ws: W1T bf16 @0 (64 KB), W2T bf16 @65536 (8 KB),
    //     Cb bf16 [100000*16] @73760 (3.2 MB), partials f32 @3273760 (12.5 KB)
    unsigned short* w1t      = (unsigned short*)d_ws;
    unsigned short* w2t      = (unsigned short*)((char*)d_ws + 65536);
    unsigned short* Cb       = (unsigned short*)((char*)d_ws + 73760);
    float*          partials = (float*)((char*)d_ws + 3273760);

    prep_kernel<<<128, 256, 0, stream>>>(W1, W2, w1t, w2t);
    mlp_kernel<<<512, 256, 0, stream>>>(x, w1t, b1, w2t, b2, out, Cb);
    edge_kernel<<<EDGE_BLOCKS, 256, 0, stream>>>(ei, Cb, partials);
    finalize_kernel<<<1, 256, 0, stream>>>(partials, out);
}